// Round 1
// baseline (440.104 us; speedup 1.0000x reference)
//
#include <hip/hip_runtime.h>

// ROIAlign: feat [B=4, C=256, H=200, W=304] fp32, rois [N=1024, 4] fp32,
// roibatches [N] int32 -> out [N, C, 7, 7] fp32.
// POOL=7x7, SCALE=0.25, SAMPLING=2 (fixed 2x2 grid per bin).

#define POOL 7
#define SAMP 2

constexpr int Cc = 256;
constexpr int Hc = 200;
constexpr int Wc = 304;
constexpr float SCALEc = 0.25f;

__global__ __launch_bounds__(256) void roialign_fwd(
    const float* __restrict__ feat,
    const float* __restrict__ rois,
    const int* __restrict__ roibatches,
    float* __restrict__ out,
    int total)
{
    int tid = blockIdx.x * blockDim.x + threadIdx.x;
    if (tid >= total) return;

    // tid == flat output index: ((n*C + c)*7 + ph)*7 + pw
    int n   = tid / (Cc * POOL * POOL);
    int rem = tid % (Cc * POOL * POOL);
    int c   = rem / (POOL * POOL);
    int bin = rem % (POOL * POOL);
    int ph  = bin / POOL;
    int pw  = bin % POOL;

    // n is wave-uniform -> these become scalar loads
    float x1 = rois[n * 4 + 0] * SCALEc;
    float y1 = rois[n * 4 + 1] * SCALEc;
    float x2 = rois[n * 4 + 2] * SCALEc;
    float y2 = rois[n * 4 + 3] * SCALEc;
    int   b  = roibatches[n];

    float roi_w = fmaxf(x2 - x1, 1.0f);
    float roi_h = fmaxf(y2 - y1, 1.0f);
    float bin_w = roi_w * (1.0f / POOL);
    float bin_h = roi_h * (1.0f / POOL);

    const float* __restrict__ fp =
        feat + (size_t)(b * Cc + c) * (size_t)(Hc * Wc);

    float acc = 0.0f;
#pragma unroll
    for (int iy = 0; iy < SAMP; ++iy) {
        float y  = y1 + ((float)ph + ((float)iy + 0.5f) * 0.5f) * bin_h;
        bool  vy = (y >= -1.0f) && (y <= (float)Hc);
        float yc = fminf(fmaxf(y, 0.0f), (float)(Hc - 1));
        int   y_lo = (int)floorf(yc);
        int   y_hi = min(y_lo + 1, Hc - 1);
        float ly = yc - (float)y_lo;
        float hy = 1.0f - ly;
        float wyl = vy ? hy : 0.0f;
        float wyh = vy ? ly : 0.0f;

        const float* __restrict__ row_lo = fp + (size_t)y_lo * Wc;
        const float* __restrict__ row_hi = fp + (size_t)y_hi * Wc;

#pragma unroll
        for (int ix = 0; ix < SAMP; ++ix) {
            float x  = x1 + ((float)pw + ((float)ix + 0.5f) * 0.5f) * bin_w;
            bool  vx = (x >= -1.0f) && (x <= (float)Wc);
            float xc = fminf(fmaxf(x, 0.0f), (float)(Wc - 1));
            int   x_lo = (int)floorf(xc);
            int   x_hi = min(x_lo + 1, Wc - 1);
            float lx = xc - (float)x_lo;
            float hx = 1.0f - lx;
            float wxl = vx ? hx : 0.0f;
            float wxh = vx ? lx : 0.0f;

            acc += wyl * (wxl * row_lo[x_lo] + wxh * row_lo[x_hi])
                 + wyh * (wxl * row_hi[x_lo] + wxh * row_hi[x_hi]);
        }
    }

    out[tid] = acc * 0.25f;  // mean over the 2x2 sampling points
}

extern "C" void kernel_launch(void* const* d_in, const int* in_sizes, int n_in,
                              void* d_out, int out_size, void* d_ws, size_t ws_size,
                              hipStream_t stream)
{
    const float* feat       = (const float*)d_in[0];
    const float* rois       = (const float*)d_in[1];
    const int*   roibatches = (const int*)d_in[2];
    float*       out        = (float*)d_out;

    int total = out_size;  // N * C * 7 * 7
    int block = 256;
    int grid  = (total + block - 1) / block;
    roialign_fwd<<<grid, block, 0, stream>>>(feat, rois, roibatches, out, total);
}

// Round 2
// 254.752 us; speedup vs baseline: 1.7276x; 1.7276x over previous
//
#include <hip/hip_runtime.h>

// ROIAlign: feat [B=4, C=256, H=200, W=304] fp32, rois [N=1024, 4] fp32,
// roibatches [N] int32 -> out [N, C, 7, 7] fp32.
// POOL=7x7, SCALE=0.25, SAMPLING=2 (fixed 2x2 grid per bin).
//
// Strategy: transpose feat NCHW -> NHWC in d_ws, then gather with
// lane = channel-group so every bilinear corner read is a fully coalesced
// 1KB wave load (64 lanes x float4 = 256 channels).

#define POOL 7

constexpr int Bc = 4;
constexpr int Cc = 256;
constexpr int Hc = 200;
constexpr int Wc = 304;
constexpr int HWc = Hc * Wc;          // 60800 (divisible by 64)
constexpr float SCALEc = 0.25f;

// ---------------- Kernel 1: NCHW -> NHWC transpose (per batch: [C,HW] -> [HW,C])
__global__ __launch_bounds__(256) void nchw_to_nhwc(
    const float* __restrict__ in, float* __restrict__ outp)
{
    __shared__ float tile[64][65];
    int b  = blockIdx.z;
    int p0 = blockIdx.x * 64;   // HW tile origin
    int c0 = blockIdx.y * 64;   // C tile origin
    int tx = threadIdx.x;       // 0..63
    int ty = threadIdx.y;       // 0..3

    const float* src = in + ((size_t)b * Cc + c0) * (size_t)HWc + p0;
#pragma unroll
    for (int k = 0; k < 16; ++k) {
        int c = ty + 4 * k;
        tile[c][tx] = src[(size_t)c * HWc + tx];
    }
    __syncthreads();
    float* dst = outp + ((size_t)b * HWc + p0) * (size_t)Cc + c0;
#pragma unroll
    for (int k = 0; k < 16; ++k) {
        int p = ty + 4 * k;
        dst[(size_t)p * Cc + tx] = tile[tx][p];
    }
}

// ---------------- Kernel 2: one wave per (roi, bin); lane = 4-channel group
__global__ __launch_bounds__(256) void roialign_nhwc(
    const float* __restrict__ fnhwc,
    const float* __restrict__ rois,
    const int*   __restrict__ roibatches,
    float* __restrict__ out)
{
    int wid  = blockIdx.x * 4 + (threadIdx.x >> 6);  // wave id = roi*49 + bin
    int lane = threadIdx.x & 63;
    int n    = wid / (POOL * POOL);
    int bin  = wid % (POOL * POOL);
    int ph   = bin / POOL;
    int pw   = bin % POOL;

    float x1 = rois[n * 4 + 0] * SCALEc;
    float y1 = rois[n * 4 + 1] * SCALEc;
    float x2 = rois[n * 4 + 2] * SCALEc;
    float y2 = rois[n * 4 + 3] * SCALEc;
    int   b  = roibatches[n];

    float roi_w = fmaxf(x2 - x1, 1.0f);
    float roi_h = fmaxf(y2 - y1, 1.0f);
    float bin_w = roi_w * (1.0f / POOL);
    float bin_h = roi_h * (1.0f / POOL);

    // per-sample y weights / rows
    int   yy[2][2];
    float wy[2][2];
#pragma unroll
    for (int iy = 0; iy < 2; ++iy) {
        float y  = y1 + ((float)ph + ((float)iy + 0.5f) * 0.5f) * bin_h;
        bool  vy = (y >= -1.0f) && (y <= (float)Hc);
        float yc = fminf(fmaxf(y, 0.0f), (float)(Hc - 1));
        int   y_lo = (int)floorf(yc);
        int   y_hi = min(y_lo + 1, Hc - 1);
        float ly = yc - (float)y_lo;
        yy[iy][0] = y_lo;           yy[iy][1] = y_hi;
        wy[iy][0] = vy ? (1.0f - ly) : 0.0f;
        wy[iy][1] = vy ? ly : 0.0f;
    }
    int   xx[2][2];
    float wx[2][2];
#pragma unroll
    for (int ix = 0; ix < 2; ++ix) {
        float x  = x1 + ((float)pw + ((float)ix + 0.5f) * 0.5f) * bin_w;
        bool  vx = (x >= -1.0f) && (x <= (float)Wc);
        float xc = fminf(fmaxf(x, 0.0f), (float)(Wc - 1));
        int   x_lo = (int)floorf(xc);
        int   x_hi = min(x_lo + 1, Wc - 1);
        float lx = xc - (float)x_lo;
        xx[ix][0] = x_lo;           xx[ix][1] = x_hi;
        wx[ix][0] = vx ? (1.0f - lx) : 0.0f;
        wx[ix][1] = vx ? lx : 0.0f;
    }

    const float* base = fnhwc + (size_t)b * ((size_t)HWc * Cc) + (size_t)lane * 4;
    float4 acc = make_float4(0.f, 0.f, 0.f, 0.f);
#pragma unroll
    for (int iy = 0; iy < 2; ++iy) {
#pragma unroll
        for (int yl = 0; yl < 2; ++yl) {
            const float* row = base + (size_t)yy[iy][yl] * ((size_t)Wc * Cc);
            float wyv = wy[iy][yl];
#pragma unroll
            for (int ix = 0; ix < 2; ++ix) {
#pragma unroll
                for (int xl = 0; xl < 2; ++xl) {
                    float w = wyv * wx[ix][xl];
                    const float4 v = *(const float4*)(row + (size_t)xx[ix][xl] * Cc);
                    acc.x = fmaf(w, v.x, acc.x);
                    acc.y = fmaf(w, v.y, acc.y);
                    acc.z = fmaf(w, v.z, acc.z);
                    acc.w = fmaf(w, v.w, acc.w);
                }
            }
        }
    }
    acc.x *= 0.25f; acc.y *= 0.25f; acc.z *= 0.25f; acc.w *= 0.25f;

    // out[((n*C + c)*49) + bin], c = lane*4 + j
    float* o = out + (size_t)n * (Cc * POOL * POOL) + (size_t)(lane * 4) * (POOL * POOL) + bin;
    o[0 * POOL * POOL] = acc.x;
    o[1 * POOL * POOL] = acc.y;
    o[2 * POOL * POOL] = acc.z;
    o[3 * POOL * POOL] = acc.w;
}

// ---------------- Fallback (round-1 kernel) if workspace is too small
__global__ __launch_bounds__(256) void roialign_fwd(
    const float* __restrict__ feat,
    const float* __restrict__ rois,
    const int* __restrict__ roibatches,
    float* __restrict__ out,
    int total)
{
    int tid = blockIdx.x * blockDim.x + threadIdx.x;
    if (tid >= total) return;
    int n   = tid / (Cc * POOL * POOL);
    int rem = tid % (Cc * POOL * POOL);
    int c   = rem / (POOL * POOL);
    int bin = rem % (POOL * POOL);
    int ph  = bin / POOL;
    int pw  = bin % POOL;

    float x1 = rois[n * 4 + 0] * SCALEc;
    float y1 = rois[n * 4 + 1] * SCALEc;
    float x2 = rois[n * 4 + 2] * SCALEc;
    float y2 = rois[n * 4 + 3] * SCALEc;
    int   b  = roibatches[n];

    float roi_w = fmaxf(x2 - x1, 1.0f);
    float roi_h = fmaxf(y2 - y1, 1.0f);
    float bin_w = roi_w * (1.0f / POOL);
    float bin_h = roi_h * (1.0f / POOL);

    const float* fp = feat + (size_t)(b * Cc + c) * (size_t)HWc;

    float acc = 0.0f;
#pragma unroll
    for (int iy = 0; iy < 2; ++iy) {
        float y  = y1 + ((float)ph + ((float)iy + 0.5f) * 0.5f) * bin_h;
        bool  vy = (y >= -1.0f) && (y <= (float)Hc);
        float yc = fminf(fmaxf(y, 0.0f), (float)(Hc - 1));
        int   y_lo = (int)floorf(yc);
        int   y_hi = min(y_lo + 1, Hc - 1);
        float ly = yc - (float)y_lo;
        float hy = 1.0f - ly;
        float wyl = vy ? hy : 0.0f;
        float wyh = vy ? ly : 0.0f;
        const float* row_lo = fp + (size_t)y_lo * Wc;
        const float* row_hi = fp + (size_t)y_hi * Wc;
#pragma unroll
        for (int ix = 0; ix < 2; ++ix) {
            float x  = x1 + ((float)pw + ((float)ix + 0.5f) * 0.5f) * bin_w;
            bool  vx = (x >= -1.0f) && (x <= (float)Wc);
            float xc = fminf(fmaxf(x, 0.0f), (float)(Wc - 1));
            int   x_lo = (int)floorf(xc);
            int   x_hi = min(x_lo + 1, Wc - 1);
            float lx = xc - (float)x_lo;
            float hx = 1.0f - lx;
            float wxl = vx ? hx : 0.0f;
            float wxh = vx ? lx : 0.0f;
            acc += wyl * (wxl * row_lo[x_lo] + wxh * row_lo[x_hi])
                 + wyh * (wxl * row_hi[x_lo] + wxh * row_hi[x_hi]);
        }
    }
    out[tid] = acc * 0.25f;
}

extern "C" void kernel_launch(void* const* d_in, const int* in_sizes, int n_in,
                              void* d_out, int out_size, void* d_ws, size_t ws_size,
                              hipStream_t stream)
{
    const float* feat       = (const float*)d_in[0];
    const float* rois       = (const float*)d_in[1];
    const int*   roibatches = (const int*)d_in[2];
    float*       out        = (float*)d_out;
    int N = in_sizes[1] / 4;

    size_t need = (size_t)Bc * Cc * HWc * sizeof(float);  // ~249 MB NHWC copy
    if (ws_size >= need) {
        float* fnhwc = (float*)d_ws;
        dim3 tgrid(HWc / 64, Cc / 64, Bc);
        dim3 tblock(64, 4);
        nchw_to_nhwc<<<tgrid, tblock, 0, stream>>>(feat, fnhwc);

        int nwaves = N * POOL * POOL;             // 50176
        int blocks = (nwaves + 3) / 4;            // 4 waves per 256-thread block
        roialign_nhwc<<<blocks, 256, 0, stream>>>(fnhwc, rois, roibatches, out);
    } else {
        int total = out_size;
        roialign_fwd<<<(total + 255) / 256, 256, 0, stream>>>(
            feat, rois, roibatches, out, total);
    }
}

// Round 3
// 129.393 us; speedup vs baseline: 3.4013x; 1.9688x over previous
//
#include <hip/hip_runtime.h>
#include <hip/hip_bf16.h>

// ROIAlign: feat [B=4, C=256, H=200, W=304] fp32, rois [N=1024,4] fp32,
// roibatches [N] int32 -> out [N, C, 7, 7] fp32.  POOL=7, SCALE=0.25, SAMP=2.
//
// Pipeline:
//  K1: NCHW fp32 -> NHWC bf16 in d_ws (124 MB, L3-resident).
//  K2: one block per roi. Wave handles 2 bins (half-wave each); lane owns
//      8 bf16 channels (one 16B load per bilinear corner -> 1KB/wave/corner,
//      fully coalesced). Results staged in LDS [49][256], then the roi's
//      50KB output chunk is written fully coalesced.

#define POOL 7
constexpr int Bc = 4;
constexpr int Cc = 256;
constexpr int Hc = 200;
constexpr int Wc = 304;
constexpr int HWc = Hc * Wc;           // 60800
constexpr float SCALEc = 0.25f;

static __device__ __forceinline__ float bf16_lo(unsigned u) {
    u <<= 16;
    return __builtin_bit_cast(float, u);
}
static __device__ __forceinline__ float bf16_hi(unsigned u) {
    u &= 0xFFFF0000u;
    return __builtin_bit_cast(float, u);
}

// ---------------- K1: NCHW fp32 -> NHWC bf16 ----------------
// Tile: 64 HW positions x 128 channels. Block 64x4.
__global__ __launch_bounds__(256) void nchw_to_nhwc_bf16(
    const float* __restrict__ in, ushort* __restrict__ outp)
{
    __shared__ float tile[128][65];
    int b  = blockIdx.z;
    int p0 = blockIdx.x * 64;    // HW origin
    int c0 = blockIdx.y * 128;   // C origin
    int tx = threadIdx.x;        // 0..63
    int ty = threadIdx.y;        // 0..3

    const float* src = in + ((size_t)b * Cc + c0) * (size_t)HWc + p0;
#pragma unroll
    for (int k = 0; k < 32; ++k) {
        int c = ty + 4 * k;                       // 0..127
        tile[c][tx] = src[(size_t)c * HWc + tx];
    }
    __syncthreads();

    // write: lane tx packs channels (2tx, 2tx+1) as one u32; 64 lanes -> 256B runs
#pragma unroll
    for (int k = 0; k < 16; ++k) {
        int p = ty + 4 * k;                       // 0..63
        float f0 = tile[2 * tx][p];
        float f1 = tile[2 * tx + 1][p];
        unsigned u0 = (unsigned)__hip_bfloat16_raw(__float2bfloat16(f0)).x;
        unsigned u1 = (unsigned)__hip_bfloat16_raw(__float2bfloat16(f1)).x;
        unsigned packed = u0 | (u1 << 16);
        size_t d = ((size_t)b * HWc + p0 + p) * (size_t)Cc + c0 + 2 * tx;
        *(unsigned*)(outp + d) = packed;
    }
}

// ---------------- K2: gather + pool, one block per roi ----------------
__global__ __launch_bounds__(256) void roialign_gather(
    const ushort* __restrict__ f,      // NHWC bf16
    const float*  __restrict__ rois,
    const int*    __restrict__ rb,
    float*        __restrict__ out)
{
    __shared__ float stage[49 * 257];  // [bin][c] padded row 257

    int n    = blockIdx.x;
    int t    = threadIdx.x;
    int wav  = t >> 6;        // 0..3
    int lane = t & 63;
    int half = lane >> 5;     // 0/1 -> which bin of the pair
    int sub  = lane & 31;     // channel group: channels sub*8 .. sub*8+7

    float x1 = rois[n * 4 + 0] * SCALEc;
    float y1 = rois[n * 4 + 1] * SCALEc;
    float x2 = rois[n * 4 + 2] * SCALEc;
    float y2 = rois[n * 4 + 3] * SCALEc;
    int   b  = rb[n];

    float roi_w = fmaxf(x2 - x1, 1.0f);
    float roi_h = fmaxf(y2 - y1, 1.0f);
    float bin_w = roi_w * (1.0f / POOL);
    float bin_h = roi_h * (1.0f / POOL);

    const ushort* base = f + (size_t)b * ((size_t)HWc * Cc) + (size_t)sub * 8;

#pragma unroll 1
    for (int it = 0; it < 7; ++it) {
        int bin = it * 8 + wav * 2 + half;   // 0..55
        if (bin < 49) {
            int ph = bin / POOL;
            int pw = bin % POOL;

            int   yy[2][2];  float wy[2][2];
#pragma unroll
            for (int iy = 0; iy < 2; ++iy) {
                float y  = y1 + ((float)ph + ((float)iy + 0.5f) * 0.5f) * bin_h;
                bool  vy = (y >= -1.0f) && (y <= (float)Hc);
                float yc = fminf(fmaxf(y, 0.0f), (float)(Hc - 1));
                int   y_lo = (int)floorf(yc);
                int   y_hi = min(y_lo + 1, Hc - 1);
                float ly = yc - (float)y_lo;
                yy[iy][0] = y_lo;  yy[iy][1] = y_hi;
                wy[iy][0] = vy ? (1.0f - ly) : 0.0f;
                wy[iy][1] = vy ? ly : 0.0f;
            }
            int   xx[2][2];  float wx[2][2];
#pragma unroll
            for (int ix = 0; ix < 2; ++ix) {
                float x  = x1 + ((float)pw + ((float)ix + 0.5f) * 0.5f) * bin_w;
                bool  vx = (x >= -1.0f) && (x <= (float)Wc);
                float xc = fminf(fmaxf(x, 0.0f), (float)(Wc - 1));
                int   x_lo = (int)floorf(xc);
                int   x_hi = min(x_lo + 1, Wc - 1);
                float lx = xc - (float)x_lo;
                xx[ix][0] = x_lo;  xx[ix][1] = x_hi;
                wx[ix][0] = vx ? (1.0f - lx) : 0.0f;
                wx[ix][1] = vx ? lx : 0.0f;
            }

            float acc[8] = {0.f, 0.f, 0.f, 0.f, 0.f, 0.f, 0.f, 0.f};
#pragma unroll
            for (int iy = 0; iy < 2; ++iy) {
#pragma unroll
                for (int yl = 0; yl < 2; ++yl) {
                    const ushort* row = base + (size_t)yy[iy][yl] * ((size_t)Wc * Cc);
                    float wyv = wy[iy][yl];
#pragma unroll
                    for (int ix = 0; ix < 2; ++ix) {
#pragma unroll
                        for (int xl = 0; xl < 2; ++xl) {
                            float w = wyv * wx[ix][xl];
                            const uint4 v = *(const uint4*)(row + (size_t)xx[ix][xl] * Cc);
                            acc[0] = fmaf(w, bf16_lo(v.x), acc[0]);
                            acc[1] = fmaf(w, bf16_hi(v.x), acc[1]);
                            acc[2] = fmaf(w, bf16_lo(v.y), acc[2]);
                            acc[3] = fmaf(w, bf16_hi(v.y), acc[3]);
                            acc[4] = fmaf(w, bf16_lo(v.z), acc[4]);
                            acc[5] = fmaf(w, bf16_hi(v.z), acc[5]);
                            acc[6] = fmaf(w, bf16_lo(v.w), acc[6]);
                            acc[7] = fmaf(w, bf16_hi(v.w), acc[7]);
                        }
                    }
                }
            }
            float* sp = &stage[bin * 257 + sub * 8];
#pragma unroll
            for (int j = 0; j < 8; ++j) sp[j] = acc[j] * 0.25f;
        }
    }
    __syncthreads();

    // coalesced write of this roi's 12544-float contiguous chunk
    float* obase = out + (size_t)n * (Cc * POOL * POOL);
#pragma unroll 1
    for (int k = 0; k < 49; ++k) {
        int flat = t + 256 * k;          // c*49 + bin
        int c    = flat / 49;
        int bin  = flat - c * 49;
        obase[flat] = stage[bin * 257 + c];
    }
}

// ---------------- Fallback (no workspace): round-1 direct kernel ----------------
__global__ __launch_bounds__(256) void roialign_fwd(
    const float* __restrict__ feat,
    const float* __restrict__ rois,
    const int* __restrict__ roibatches,
    float* __restrict__ out,
    int total)
{
    int tid = blockIdx.x * blockDim.x + threadIdx.x;
    if (tid >= total) return;
    int n   = tid / (Cc * POOL * POOL);
    int rem = tid % (Cc * POOL * POOL);
    int c   = rem / (POOL * POOL);
    int bin = rem % (POOL * POOL);
    int ph  = bin / POOL;
    int pw  = bin % POOL;

    float x1 = rois[n * 4 + 0] * SCALEc;
    float y1 = rois[n * 4 + 1] * SCALEc;
    float x2 = rois[n * 4 + 2] * SCALEc;
    float y2 = rois[n * 4 + 3] * SCALEc;
    int   b  = roibatches[n];

    float roi_w = fmaxf(x2 - x1, 1.0f);
    float roi_h = fmaxf(y2 - y1, 1.0f);
    float bin_w = roi_w * (1.0f / POOL);
    float bin_h = roi_h * (1.0f / POOL);

    const float* fp = feat + (size_t)(b * Cc + c) * (size_t)HWc;

    float acc = 0.0f;
#pragma unroll
    for (int iy = 0; iy < 2; ++iy) {
        float y  = y1 + ((float)ph + ((float)iy + 0.5f) * 0.5f) * bin_h;
        bool  vy = (y >= -1.0f) && (y <= (float)Hc);
        float yc = fminf(fmaxf(y, 0.0f), (float)(Hc - 1));
        int   y_lo = (int)floorf(yc);
        int   y_hi = min(y_lo + 1, Hc - 1);
        float ly = yc - (float)y_lo;
        float hy = 1.0f - ly;
        float wyl = vy ? hy : 0.0f;
        float wyh = vy ? ly : 0.0f;
        const float* row_lo = fp + (size_t)y_lo * Wc;
        const float* row_hi = fp + (size_t)y_hi * Wc;
#pragma unroll
        for (int ix = 0; ix < 2; ++ix) {
            float x  = x1 + ((float)pw + ((float)ix + 0.5f) * 0.5f) * bin_w;
            bool  vx = (x >= -1.0f) && (x <= (float)Wc);
            float xc = fminf(fmaxf(x, 0.0f), (float)(Wc - 1));
            int   x_lo = (int)floorf(xc);
            int   x_hi = min(x_lo + 1, Wc - 1);
            float lx = xc - (float)x_lo;
            float hx = 1.0f - lx;
            float wxl = vx ? hx : 0.0f;
            float wxh = vx ? lx : 0.0f;
            acc += wyl * (wxl * row_lo[x_lo] + wxh * row_lo[x_hi])
                 + wyh * (wxl * row_hi[x_lo] + wxh * row_hi[x_hi]);
        }
    }
    out[tid] = acc * 0.25f;
}

extern "C" void kernel_launch(void* const* d_in, const int* in_sizes, int n_in,
                              void* d_out, int out_size, void* d_ws, size_t ws_size,
                              hipStream_t stream)
{
    const float* feat       = (const float*)d_in[0];
    const float* rois       = (const float*)d_in[1];
    const int*   roibatches = (const int*)d_in[2];
    float*       out        = (float*)d_out;
    int N = in_sizes[1] / 4;

    size_t need = (size_t)Bc * HWc * Cc * sizeof(ushort);  // ~124.5 MB
    if (ws_size >= need) {
        ushort* fbh = (ushort*)d_ws;
        dim3 tgrid(HWc / 64, Cc / 128, Bc);
        dim3 tblock(64, 4);
        nchw_to_nhwc_bf16<<<tgrid, tblock, 0, stream>>>(feat, fbh);

        roialign_gather<<<N, 256, 0, stream>>>(fbh, rois, roibatches, out);
    } else {
        int total = out_size;
        roialign_fwd<<<(total + 255) / 256, 256, 0, stream>>>(
            feat, rois, roibatches, out, total);
    }
}

// Round 4
// 124.068 us; speedup vs baseline: 3.5473x; 1.0429x over previous
//
#include <hip/hip_runtime.h>
#include <hip/hip_bf16.h>

// ROIAlign: feat [B=4, C=256, H=200, W=304] fp32, rois [N=1024,4] fp32,
// roibatches [N] int32 -> out [N, C, 7, 7] fp32.  POOL=7, SCALE=0.25, SAMP=2.
//
// K1: NCHW fp32 -> NHWC bf16 (d_ws, 124 MB, L3-resident). 1KB/wave writes.
// K2: one block (512 thr) per roi; half-wave = bin, lane owns 8 bf16 channels.
//     8 corner loads batched per y-sample for ILP. Results staged in LDS
//     [49][256] then written as one contiguous 50KB chunk.

#define POOL 7
constexpr int Bc = 4;
constexpr int Cc = 256;
constexpr int Hc = 200;
constexpr int Wc = 304;
constexpr int HWc = Hc * Wc;           // 60800
constexpr float SCALEc = 0.25f;

static __device__ __forceinline__ float bf16_lo(unsigned u) {
    u <<= 16;
    return __builtin_bit_cast(float, u);
}
static __device__ __forceinline__ float bf16_hi(unsigned u) {
    u &= 0xFFFF0000u;
    return __builtin_bit_cast(float, u);
}
static __device__ __forceinline__ unsigned pack_bf16(float f0, float f1) {
    unsigned u0 = (unsigned)__hip_bfloat16_raw(__float2bfloat16(f0)).x;
    unsigned u1 = (unsigned)__hip_bfloat16_raw(__float2bfloat16(f1)).x;
    return u0 | (u1 << 16);
}

// ---------------- K1: NCHW fp32 -> NHWC bf16 ----------------
// Tile: 128 channels x 64 HW positions. Block (64,4).
// LDS XOR swizzle (p ^ ((c>>5)&3)) makes the transposed read conflict-free.
__global__ __launch_bounds__(256) void nchw_to_nhwc_bf16(
    const float* __restrict__ in, ushort* __restrict__ outp)
{
    __shared__ float tile[128][65];
    int b  = blockIdx.z;
    int p0 = blockIdx.x * 64;    // HW origin
    int c0 = blockIdx.y * 128;   // C origin
    int tx = threadIdx.x;        // 0..63
    int ty = threadIdx.y;        // 0..3

    const float* src = in + ((size_t)b * Cc + c0) * (size_t)HWc + p0;
#pragma unroll
    for (int k = 0; k < 32; ++k) {
        int c = ty + 4 * k;                       // 0..127
        tile[c][tx ^ ((c >> 5) & 3)] = src[(size_t)c * HWc + tx];
    }
    __syncthreads();

    // write: lane packs 8 channels (uint4 = 16B) -> 1KB per wave store
    int t  = ty * 64 + tx;       // 0..255
    int cg = t & 15;             // 8-channel group
    int pi = t >> 4;             // 0..15
#pragma unroll
    for (int k = 0; k < 4; ++k) {
        int p = pi + 16 * k;     // 0..63
        unsigned u[4];
#pragma unroll
        for (int j = 0; j < 4; ++j) {
            int ce = cg * 8 + 2 * j;
            int co = ce + 1;
            float f0 = tile[ce][p ^ ((ce >> 5) & 3)];
            float f1 = tile[co][p ^ ((co >> 5) & 3)];
            u[j] = pack_bf16(f0, f1);
        }
        size_t d = ((size_t)b * HWc + p0 + p) * (size_t)Cc + c0 + cg * 8;
        *(uint4*)(outp + d) = make_uint4(u[0], u[1], u[2], u[3]);
    }
}

// ---------------- K2: gather + pool, one block (512 thr) per roi ----------------
__global__ __launch_bounds__(512) void roialign_gather(
    const ushort* __restrict__ f,      // NHWC bf16
    const float*  __restrict__ rois,
    const int*    __restrict__ rb,
    float*        __restrict__ out)
{
    __shared__ float stage[49 * 257];  // [bin][c], row pad 257

    int n    = blockIdx.x;
    int t    = threadIdx.x;   // 0..511
    int wav  = t >> 6;        // 0..7
    int lane = t & 63;
    int half = lane >> 5;     // which bin of the wave's pair
    int sub  = lane & 31;     // channels sub*8 .. sub*8+7

    float x1 = rois[n * 4 + 0] * SCALEc;
    float y1 = rois[n * 4 + 1] * SCALEc;
    float x2 = rois[n * 4 + 2] * SCALEc;
    float y2 = rois[n * 4 + 3] * SCALEc;
    int   b  = rb[n];

    float roi_w = fmaxf(x2 - x1, 1.0f);
    float roi_h = fmaxf(y2 - y1, 1.0f);
    float bin_w = roi_w * (1.0f / POOL);
    float bin_h = roi_h * (1.0f / POOL);

    const ushort* base = f + (size_t)b * ((size_t)HWc * Cc) + (size_t)sub * 8;

#pragma unroll 1
    for (int it = 0; it < 4; ++it) {
        int bin = it * 16 + wav * 2 + half;   // 0..63
        if (bin < 49) {
            int ph = bin / POOL;
            int pw = bin % POOL;

            int   yy[2][2];  float wy[2][2];
#pragma unroll
            for (int iy = 0; iy < 2; ++iy) {
                float y  = y1 + ((float)ph + ((float)iy + 0.5f) * 0.5f) * bin_h;
                bool  vy = (y >= -1.0f) && (y <= (float)Hc);
                float yc = fminf(fmaxf(y, 0.0f), (float)(Hc - 1));
                int   y_lo = (int)floorf(yc);
                int   y_hi = min(y_lo + 1, Hc - 1);
                float ly = yc - (float)y_lo;
                yy[iy][0] = y_lo;  yy[iy][1] = y_hi;
                wy[iy][0] = vy ? (1.0f - ly) : 0.0f;
                wy[iy][1] = vy ? ly : 0.0f;
            }
            int   xx[2][2];  float wx[2][2];
#pragma unroll
            for (int ix = 0; ix < 2; ++ix) {
                float x  = x1 + ((float)pw + ((float)ix + 0.5f) * 0.5f) * bin_w;
                bool  vx = (x >= -1.0f) && (x <= (float)Wc);
                float xc = fminf(fmaxf(x, 0.0f), (float)(Wc - 1));
                int   x_lo = (int)floorf(xc);
                int   x_hi = min(x_lo + 1, Wc - 1);
                float lx = xc - (float)x_lo;
                xx[ix][0] = x_lo;  xx[ix][1] = x_hi;
                wx[ix][0] = vx ? (1.0f - lx) : 0.0f;
                wx[ix][1] = vx ? lx : 0.0f;
            }

            float acc[8] = {0.f, 0.f, 0.f, 0.f, 0.f, 0.f, 0.f, 0.f};
#pragma unroll
            for (int iy = 0; iy < 2; ++iy) {
                // batch the 8 corner loads of this y-sample, then FMA
                uint4 v[2][4];
#pragma unroll
                for (int yl = 0; yl < 2; ++yl) {
                    const ushort* row = base + (size_t)yy[iy][yl] * ((size_t)Wc * Cc);
#pragma unroll
                    for (int q = 0; q < 4; ++q) {
                        int ix = q >> 1, xl = q & 1;
                        v[yl][q] = *(const uint4*)(row + (size_t)xx[ix][xl] * Cc);
                    }
                }
#pragma unroll
                for (int yl = 0; yl < 2; ++yl) {
#pragma unroll
                    for (int q = 0; q < 4; ++q) {
                        int ix = q >> 1, xl = q & 1;
                        float w = wy[iy][yl] * wx[ix][xl];
                        const uint4 vv = v[yl][q];
                        acc[0] = fmaf(w, bf16_lo(vv.x), acc[0]);
                        acc[1] = fmaf(w, bf16_hi(vv.x), acc[1]);
                        acc[2] = fmaf(w, bf16_lo(vv.y), acc[2]);
                        acc[3] = fmaf(w, bf16_hi(vv.y), acc[3]);
                        acc[4] = fmaf(w, bf16_lo(vv.z), acc[4]);
                        acc[5] = fmaf(w, bf16_hi(vv.z), acc[5]);
                        acc[6] = fmaf(w, bf16_lo(vv.w), acc[6]);
                        acc[7] = fmaf(w, bf16_hi(vv.w), acc[7]);
                    }
                }
            }
            float* sp = &stage[bin * 257 + sub * 8];
#pragma unroll
            for (int j = 0; j < 8; ++j) sp[j] = acc[j] * 0.25f;
        }
    }
    __syncthreads();

    // coalesced write of this roi's 12544-float contiguous chunk
    float* obase = out + (size_t)n * (Cc * POOL * POOL);
#pragma unroll 1
    for (int k = 0; k < 25; ++k) {
        int flat = t + 512 * k;          // c*49 + bin
        if (flat < Cc * POOL * POOL) {
            int c   = flat / 49;
            int bin = flat - c * 49;
            obase[flat] = stage[bin * 257 + c];
        }
    }
}

// ---------------- Fallback (no workspace): direct NCHW kernel ----------------
__global__ __launch_bounds__(256) void roialign_fwd(
    const float* __restrict__ feat,
    const float* __restrict__ rois,
    const int* __restrict__ roibatches,
    float* __restrict__ out,
    int total)
{
    int tid = blockIdx.x * blockDim.x + threadIdx.x;
    if (tid >= total) return;
    int n   = tid / (Cc * POOL * POOL);
    int rem = tid % (Cc * POOL * POOL);
    int c   = rem / (POOL * POOL);
    int bin = rem % (POOL * POOL);
    int ph  = bin / POOL;
    int pw  = bin % POOL;

    float x1 = rois[n * 4 + 0] * SCALEc;
    float y1 = rois[n * 4 + 1] * SCALEc;
    float x2 = rois[n * 4 + 2] * SCALEc;
    float y2 = rois[n * 4 + 3] * SCALEc;
    int   b  = roibatches[n];

    float roi_w = fmaxf(x2 - x1, 1.0f);
    float roi_h = fmaxf(y2 - y1, 1.0f);
    float bin_w = roi_w * (1.0f / POOL);
    float bin_h = roi_h * (1.0f / POOL);

    const float* fp = feat + (size_t)(b * Cc + c) * (size_t)HWc;

    float acc = 0.0f;
#pragma unroll
    for (int iy = 0; iy < 2; ++iy) {
        float y  = y1 + ((float)ph + ((float)iy + 0.5f) * 0.5f) * bin_h;
        bool  vy = (y >= -1.0f) && (y <= (float)Hc);
        float yc = fminf(fmaxf(y, 0.0f), (float)(Hc - 1));
        int   y_lo = (int)floorf(yc);
        int   y_hi = min(y_lo + 1, Hc - 1);
        float ly = yc - (float)y_lo;
        float hy = 1.0f - ly;
        float wyl = vy ? hy : 0.0f;
        float wyh = vy ? ly : 0.0f;
        const float* row_lo = fp + (size_t)y_lo * Wc;
        const float* row_hi = fp + (size_t)y_hi * Wc;
#pragma unroll
        for (int ix = 0; ix < 2; ++ix) {
            float x  = x1 + ((float)pw + ((float)ix + 0.5f) * 0.5f) * bin_w;
            bool  vx = (x >= -1.0f) && (x <= (float)Wc);
            float xc = fminf(fmaxf(x, 0.0f), (float)(Wc - 1));
            int   x_lo = (int)floorf(xc);
            int   x_hi = min(x_lo + 1, Wc - 1);
            float lx = xc - (float)x_lo;
            float hx = 1.0f - lx;
            float wxl = vx ? hx : 0.0f;
            float wxh = vx ? lx : 0.0f;
            acc += wyl * (wxl * row_lo[x_lo] + wxh * row_lo[x_hi])
                 + wyh * (wxl * row_hi[x_lo] + wxh * row_hi[x_hi]);
        }
    }
    out[tid] = acc * 0.25f;
}

extern "C" void kernel_launch(void* const* d_in, const int* in_sizes, int n_in,
                              void* d_out, int out_size, void* d_ws, size_t ws_size,
                              hipStream_t stream)
{
    const float* feat       = (const float*)d_in[0];
    const float* rois       = (const float*)d_in[1];
    const int*   roibatches = (const int*)d_in[2];
    float*       out        = (float*)d_out;
    int N = in_sizes[1] / 4;

    size_t need = (size_t)Bc * HWc * Cc * sizeof(ushort);  // ~124.5 MB
    if (ws_size >= need) {
        ushort* fbh = (ushort*)d_ws;
        dim3 tgrid(HWc / 64, Cc / 128, Bc);
        dim3 tblock(64, 4);
        nchw_to_nhwc_bf16<<<tgrid, tblock, 0, stream>>>(feat, fbh);

        roialign_gather<<<N, 512, 0, stream>>>(fbh, rois, roibatches, out);
    } else {
        int total = out_size;
        roialign_fwd<<<(total + 255) / 256, 256, 0, stream>>>(
            feat, rois, roibatches, out, total);
    }
}